// Round 7
// baseline (35.537 us; speedup 1.0000x reference)
//
#include <hip/hip_runtime.h>

// YOLO loss: S=28, B=2, NUM_CLASSES=20, L_COORD=5, L_NOOBJ=0.5, N=1024
// Inputs (fp32 unless noted):
//   d_in[0] pred_tensor  (N,28,28,30)
//   d_in[1] target_boxes (N,28,28,4)
//   d_in[2] target_cls   (N,28,28,20)
//   d_in[3] has_object_map (N,28,28) bool -> int32 on device
// Output: 5 floats [total, reg, contain, noobj, cls]
//
// R7 = R6 insight taken to the limit. Only conf0/conf1 are needed by ALL
// lanes; stage JUST those through LDS (2 KB vs 31 KB) so LDS stops
// capping occupancy (20 -> 32 waves/CU). The 25% object lanes read
// box/cls/tbox/tcls directly from global (L2/L3-resident, exec-masked,
// latency hidden by the extra waves).
// Ladder: R1 38.5 / R2 35.5 / R3 133 (fence!) / R4 60 (atomics) /
// R5 58 (pairing broke L3) / R6 31.2 (predication) / R7: occupancy.

__device__ inline float wave_reduce(float v) {
    #pragma unroll
    for (int off = 32; off > 0; off >>= 1)
        v += __shfl_down(v, off, 64);
    return v;
}

__global__ void __launch_bounds__(256) yolo_partial(
    const float* __restrict__ pred,
    const float* __restrict__ tbox,
    const float* __restrict__ tcls,
    const int*  __restrict__ mask,
    float* __restrict__ partial, int ncells)
{
    __shared__ float sconf[512];            // 256 cells x {conf0, conf1}
    const float inv_s = 1.0f / 28.0f;

    const int base = blockIdx.x * 256;
    const int nc   = min(256, ncells - base);

    // ---- stage conf words only: per 2-cell group (30 float2), conf words
    // live at float2 idx {2,4,17,19} (.x,.y,.x,.y). j = 4*group + q.
    if (nc == 256) {
        const float2* g2 = (const float2*)pred + (size_t)blockIdx.x * 3840;
        #pragma unroll
        for (int i = 0; i < 2; ++i) {
            int j = threadIdx.x + i * 256;      // 0..511
            int g = j >> 2, q = j & 3;
            static const int qmap[4] = {2, 4, 17, 19};
            float2 v = g2[g * 30 + qmap[q]];
            sconf[j] = (q & 1) ? v.y : v.x;
        }
    } else {
        for (int w = threadIdx.x; w < nc * 2; w += 256) {
            int i = w >> 1, k = w & 1;
            sconf[w] = pred[(size_t)(base + i) * 30 + (k ? 9 : 4)];
        }
    }
    __syncthreads();

    float s_cls = 0.f, s_noobj = 0.f, s_contain = 0.f, s_reg = 0.f;

    const int cell = base + threadIdx.x;
    if (threadIdx.x < nc) {
        float conf0 = sconf[2 * threadIdx.x];
        float conf1 = sconf[2 * threadIdx.x + 1];

        if (mask[cell] == 0) {
            // ---- no-object path (75% of lanes): conf only
            s_noobj = conf0*conf0 + conf1*conf1;   // x0.5 at the end
        } else {
            // ---- object path (25% of lanes): read this cell direct from
            // global (8B-aligned float2; L2/L3-resident under exec mask)
            const float2* pp = (const float2*)(pred + (size_t)cell * 30);
            float2 b0 = pp[0], b1 = pp[1], b2 = pp[2], b3 = pp[3], b4 = pp[4];
            // box0 = (b0.x, b0.y, b1.x, b1.y, conf0)
            // box1 = (b2.y, b3.x, b3.y, b4.x, conf1)

            // class loss: pred floats 10..29 (float2 idx 5..14) vs tcls
            float pc[20];
            #pragma unroll
            for (int k = 0; k < 10; k++) {
                float2 t = pp[5 + k];
                pc[2*k] = t.x; pc[2*k+1] = t.y;
            }
            const float4* c4 = (const float4*)tcls + (size_t)cell * 5;
            float cl = 0.f;
            #pragma unroll
            for (int k = 0; k < 5; k++) {
                float4 t = c4[k];
                float d0 = pc[4*k+0] - t.x, d1 = pc[4*k+1] - t.y;
                float d2 = pc[4*k+2] - t.z, d3 = pc[4*k+3] - t.w;
                cl += d0*d0 + d1*d1 + d2*d2 + d3*d3;
            }
            s_cls = cl;

            // target box -> xyxy
            float4 tb = ((const float4*)tbox)[cell];
            float tx = tb.x * inv_s, ty = tb.y * inv_s;
            float tx1 = tx - 0.5f*tb.z, ty1 = ty - 0.5f*tb.w;
            float tx2 = tx + 0.5f*tb.z, ty2 = ty + 0.5f*tb.w;
            float area_t = (tx2 - tx1) * (ty2 - ty1);

            // IoU of both pred boxes vs target
            float bxv[2] = {b0.x, b2.y}, byv[2] = {b0.y, b3.x};
            float bwv[2] = {b1.x, b3.y}, bhv[2] = {b1.y, b4.x};
            float confv[2] = {conf0, conf1};
            float iou[2];
            #pragma unroll
            for (int b = 0; b < 2; b++) {
                float px = bxv[b] * inv_s, py = byv[b] * inv_s;
                float px1 = px - 0.5f*bwv[b], py1 = py - 0.5f*bhv[b];
                float px2 = px + 0.5f*bwv[b], py2 = py + 0.5f*bhv[b];
                float ltx = fmaxf(px1, tx1), lty = fmaxf(py1, ty1);
                float rbx = fminf(px2, tx2), rby = fminf(py2, ty2);
                float w = fmaxf(rbx - ltx, 0.f), h = fmaxf(rby - lty, 0.f);
                float inter = w * h;
                float area_p = (px2 - px1) * (py2 - py1);
                iou[b] = inter / (area_p + area_t - inter);
            }
            int bi = (iou[1] > iou[0]) ? 1 : 0;   // argmax: first on ties
            float biou = fmaxf(iou[0], iou[1]);

            float bbx = bxv[bi], bby = byv[bi], bbw = bwv[bi], bbh = bhv[bi], bconf = confv[bi];

            // regression loss (x5 at the end)
            float dx = bbx - tb.x, dy = bby - tb.y;
            float center = dx*dx + dy*dy;
            float sw = sqrtf(fmaxf(bbw, 0.f)) - sqrtf(tb.z);
            float sh = sqrtf(fmaxf(bbh, 0.f)) - sqrtf(tb.w);
            s_reg = center + sw*sw + sh*sh;

            // containment loss
            float dc = bconf - biou;
            s_contain = dc * dc;
        }
    }

    // ---- block reduce: 4 waves x 4 sums
    __shared__ float red[4][4];
    int lane = threadIdx.x & 63, wid = threadIdx.x >> 6;
    s_cls = wave_reduce(s_cls);
    s_noobj = wave_reduce(s_noobj);
    s_contain = wave_reduce(s_contain);
    s_reg = wave_reduce(s_reg);
    if (lane == 0) {
        red[wid][0] = s_cls; red[wid][1] = s_noobj;
        red[wid][2] = s_contain; red[wid][3] = s_reg;
    }
    __syncthreads();
    if (threadIdx.x < 4) {
        float acc = red[0][threadIdx.x] + red[1][threadIdx.x]
                  + red[2][threadIdx.x] + red[3][threadIdx.x];
        partial[(size_t)blockIdx.x * 4 + threadIdx.x] = acc;
    }
}

__global__ void __launch_bounds__(256) yolo_final(
    const float* __restrict__ partial, int nblocks, float* __restrict__ out)
{
    float s0 = 0.f, s1 = 0.f, s2 = 0.f, s3 = 0.f;
    const float4* p4 = (const float4*)partial;
    for (int i = threadIdx.x; i < nblocks; i += 256) {
        float4 t = p4[i];
        s0 += t.x; s1 += t.y; s2 += t.z; s3 += t.w;
    }
    __shared__ float red[4][4];
    int lane = threadIdx.x & 63, wid = threadIdx.x >> 6;
    s0 = wave_reduce(s0); s1 = wave_reduce(s1);
    s2 = wave_reduce(s2); s3 = wave_reduce(s3);
    if (lane == 0) { red[wid][0]=s0; red[wid][1]=s1; red[wid][2]=s2; red[wid][3]=s3; }
    __syncthreads();
    if (threadIdx.x == 0) {
        float cls = 0.f, noobj = 0.f, contain = 0.f, reg = 0.f;
        #pragma unroll
        for (int w = 0; w < 4; w++) {
            cls += red[w][0]; noobj += red[w][1];
            contain += red[w][2]; reg += red[w][3];
        }
        noobj *= 0.5f;   // L_NOOBJ
        reg   *= 5.0f;   // L_COORD
        float total = (cls + noobj + contain + reg) / 1024.0f;
        out[0] = total; out[1] = reg; out[2] = contain;
        out[3] = noobj; out[4] = cls;
    }
}

extern "C" void kernel_launch(void* const* d_in, const int* in_sizes, int n_in,
                              void* d_out, int out_size, void* d_ws, size_t ws_size,
                              hipStream_t stream) {
    const float* pred = (const float*)d_in[0];
    const float* tbox = (const float*)d_in[1];
    const float* tcls = (const float*)d_in[2];
    const int*   mask = (const int*)d_in[3];

    int ncells = in_sizes[3];                 // N * S * S = 802816
    int nblocks = (ncells + 255) / 256;       // 3136
    int maxblocks = (int)(ws_size / (4 * sizeof(float)));
    if (nblocks > maxblocks) nblocks = maxblocks;
    if (nblocks < 1) nblocks = 1;

    yolo_partial<<<nblocks, 256, 0, stream>>>(
        pred, tbox, tcls, mask, (float*)d_ws, ncells);
    yolo_final<<<1, 256, 0, stream>>>((float*)d_ws, nblocks, (float*)d_out);
}

// Round 8
// 34.861 us; speedup vs baseline: 1.0194x; 1.0194x over previous
//
#include <hip/hip_runtime.h>

// YOLO loss: S=28, B=2, NUM_CLASSES=20, L_COORD=5, L_NOOBJ=0.5, N=1024
// Inputs (fp32 unless noted):
//   d_in[0] pred_tensor  (N,28,28,30)
//   d_in[1] target_boxes (N,28,28,4)
//   d_in[2] target_cls   (N,28,28,20)
//   d_in[3] has_object_map (N,28,28) bool -> int32 on device
// Output: 5 floats [total, reg, contain, noobj, cls]
//
// R8 = R6 + occupancy fix. Inputs are L3-resident in bench mode (FETCH
// 70MB < 176MB logical) -> latency-bound, occupancy is the lever.
// Stage only the box+conf words (floats 0..9, 40B/cell) in LDS with
// stride 11 (coprime 32 -> conflict-free reads; R6 had 114K conflict
// cycles). LDS 31KB -> 11KB: 5 -> 8 blocks/CU = 32 waves (100% cap).
// Object lanes (25%, exec-masked) read the cls half direct from global
// (L3-resident). Every 128B pred line holds some cell's box words, so
// staging still touches all pred lines -> FETCH unchanged.
// Ladder: R2 35.5 / R6 31.2 (best) / R7 35.5 (conf-only staging: bad).

__device__ inline float wave_reduce(float v) {
    #pragma unroll
    for (int off = 32; off > 0; off >>= 1)
        v += __shfl_down(v, off, 64);
    return v;
}

__global__ void __launch_bounds__(256) yolo_partial(
    const float* __restrict__ pred,
    const float* __restrict__ tbox,
    const float* __restrict__ tcls,
    const int*  __restrict__ mask,
    float* __restrict__ partial, int ncells)
{
    __shared__ float sb[256 * 11];          // 11264 B; words 0..9 per cell
    const float inv_s = 1.0f / 28.0f;

    const int base = blockIdx.x * 256;
    const int nc   = min(256, ncells - base);

    // ---- stage box+conf words (float2 idx 0..4 of each 15-float2 cell) ----
    if (nc == 256) {
        const float2* g2 = (const float2*)pred + (size_t)base * 15;
        #pragma unroll
        for (int i = 0; i < 5; ++i) {
            int j = threadIdx.x + i * 256;      // 0..1279
            int cell = j / 5;                   // magic-mul
            int off  = j - cell * 5;            // 0..4
            float2 v = g2[cell * 15 + off];
            sb[cell * 11 + 2 * off]     = v.x;  // banks spread: 11 coprime 32
            sb[cell * 11 + 2 * off + 1] = v.y;
        }
    } else {
        for (int w = threadIdx.x; w < nc * 10; w += 256) {
            int i = w / 10, k = w - i * 10;
            sb[i * 11 + k] = pred[(size_t)(base + i) * 30 + k];
        }
    }
    __syncthreads();

    float s_cls = 0.f, s_noobj = 0.f, s_contain = 0.f, s_reg = 0.f;

    const int cell = base + threadIdx.x;
    if (threadIdx.x < nc) {
        const float* w = sb + threadIdx.x * 11; // [x0,y0,w0,h0,c0, x1,y1,w1,h1,c1]
        float conf0 = w[4], conf1 = w[9];

        if (mask[cell] == 0) {
            // ---- no-object path (75% of lanes): conf only
            s_noobj = conf0*conf0 + conf1*conf1;   // x0.5 at the end
        } else {
            // ---- object path (25%): cls from global (L3-resident, masked)
            float pc[20];
            const float2* pcls = (const float2*)(pred + (size_t)cell * 30 + 10);
            #pragma unroll
            for (int k = 0; k < 10; k++) {
                float2 t = pcls[k];
                pc[2*k] = t.x; pc[2*k+1] = t.y;
            }
            const float4* c4 = (const float4*)tcls + (size_t)cell * 5;
            float cl = 0.f;
            #pragma unroll
            for (int k = 0; k < 5; k++) {
                float4 t = c4[k];
                float d0 = pc[4*k+0] - t.x, d1 = pc[4*k+1] - t.y;
                float d2 = pc[4*k+2] - t.z, d3 = pc[4*k+3] - t.w;
                cl += d0*d0 + d1*d1 + d2*d2 + d3*d3;
            }
            s_cls = cl;

            // target box -> xyxy
            float4 tb = ((const float4*)tbox)[cell];
            float tx = tb.x * inv_s, ty = tb.y * inv_s;
            float tx1 = tx - 0.5f*tb.z, ty1 = ty - 0.5f*tb.w;
            float tx2 = tx + 0.5f*tb.z, ty2 = ty + 0.5f*tb.w;
            float area_t = (tx2 - tx1) * (ty2 - ty1);

            // IoU of both pred boxes vs target
            float bxv[2] = {w[0], w[5]}, byv[2] = {w[1], w[6]};
            float bwv[2] = {w[2], w[7]}, bhv[2] = {w[3], w[8]};
            float confv[2] = {conf0, conf1};
            float iou[2];
            #pragma unroll
            for (int b = 0; b < 2; b++) {
                float px = bxv[b] * inv_s, py = byv[b] * inv_s;
                float px1 = px - 0.5f*bwv[b], py1 = py - 0.5f*bhv[b];
                float px2 = px + 0.5f*bwv[b], py2 = py + 0.5f*bhv[b];
                float ltx = fmaxf(px1, tx1), lty = fmaxf(py1, ty1);
                float rbx = fminf(px2, tx2), rby = fminf(py2, ty2);
                float ww = fmaxf(rbx - ltx, 0.f), hh = fmaxf(rby - lty, 0.f);
                float inter = ww * hh;
                float area_p = (px2 - px1) * (py2 - py1);
                iou[b] = inter / (area_p + area_t - inter);
            }
            int bi = (iou[1] > iou[0]) ? 1 : 0;   // argmax: first on ties
            float biou = fmaxf(iou[0], iou[1]);

            float bbx = bxv[bi], bby = byv[bi], bbw = bwv[bi], bbh = bhv[bi], bconf = confv[bi];

            // regression loss (x5 at the end)
            float dx = bbx - tb.x, dy = bby - tb.y;
            float center = dx*dx + dy*dy;
            float sw = sqrtf(fmaxf(bbw, 0.f)) - sqrtf(tb.z);
            float sh = sqrtf(fmaxf(bbh, 0.f)) - sqrtf(tb.w);
            s_reg = center + sw*sw + sh*sh;

            // containment loss
            float dc = bconf - biou;
            s_contain = dc * dc;
        }
    }

    // ---- block reduce: 4 waves x 4 sums
    __shared__ float red[4][4];
    int lane = threadIdx.x & 63, wid = threadIdx.x >> 6;
    s_cls = wave_reduce(s_cls);
    s_noobj = wave_reduce(s_noobj);
    s_contain = wave_reduce(s_contain);
    s_reg = wave_reduce(s_reg);
    if (lane == 0) {
        red[wid][0] = s_cls; red[wid][1] = s_noobj;
        red[wid][2] = s_contain; red[wid][3] = s_reg;
    }
    __syncthreads();
    if (threadIdx.x < 4) {
        float acc = red[0][threadIdx.x] + red[1][threadIdx.x]
                  + red[2][threadIdx.x] + red[3][threadIdx.x];
        partial[(size_t)blockIdx.x * 4 + threadIdx.x] = acc;
    }
}

__global__ void __launch_bounds__(256) yolo_final(
    const float* __restrict__ partial, int nblocks, float* __restrict__ out)
{
    float s0 = 0.f, s1 = 0.f, s2 = 0.f, s3 = 0.f;
    const float4* p4 = (const float4*)partial;
    for (int i = threadIdx.x; i < nblocks; i += 256) {
        float4 t = p4[i];
        s0 += t.x; s1 += t.y; s2 += t.z; s3 += t.w;
    }
    __shared__ float red[4][4];
    int lane = threadIdx.x & 63, wid = threadIdx.x >> 6;
    s0 = wave_reduce(s0); s1 = wave_reduce(s1);
    s2 = wave_reduce(s2); s3 = wave_reduce(s3);
    if (lane == 0) { red[wid][0]=s0; red[wid][1]=s1; red[wid][2]=s2; red[wid][3]=s3; }
    __syncthreads();
    if (threadIdx.x == 0) {
        float cls = 0.f, noobj = 0.f, contain = 0.f, reg = 0.f;
        #pragma unroll
        for (int w = 0; w < 4; w++) {
            cls += red[w][0]; noobj += red[w][1];
            contain += red[w][2]; reg += red[w][3];
        }
        noobj *= 0.5f;   // L_NOOBJ
        reg   *= 5.0f;   // L_COORD
        float total = (cls + noobj + contain + reg) / 1024.0f;
        out[0] = total; out[1] = reg; out[2] = contain;
        out[3] = noobj; out[4] = cls;
    }
}

extern "C" void kernel_launch(void* const* d_in, const int* in_sizes, int n_in,
                              void* d_out, int out_size, void* d_ws, size_t ws_size,
                              hipStream_t stream) {
    const float* pred = (const float*)d_in[0];
    const float* tbox = (const float*)d_in[1];
    const float* tcls = (const float*)d_in[2];
    const int*   mask = (const int*)d_in[3];

    int ncells = in_sizes[3];                 // N * S * S = 802816
    int nblocks = (ncells + 255) / 256;       // 3136
    int maxblocks = (int)(ws_size / (4 * sizeof(float)));
    if (nblocks > maxblocks) nblocks = maxblocks;
    if (nblocks < 1) nblocks = 1;

    yolo_partial<<<nblocks, 256, 0, stream>>>(
        pred, tbox, tcls, mask, (float*)d_ws, ncells);
    yolo_final<<<1, 256, 0, stream>>>((float*)d_ws, nblocks, (float*)d_out);
}